// Round 1
// baseline (463.318 us; speedup 1.0000x reference)
//
#include <hip/hip_runtime.h>

// Problem constants (match reference)
constexpr int NB = 16384;   // B
constexpr int NK = 50;      // K
constexpr int NH = 64;      // H
constexpr float REG = 0.01f;
constexpr int NGRP = 13;    // ceil(NK/4) row-groups (quarter-wave = one row)

// acc[0] = sum (pred-target)^2 over B*K
// acc[1] = sum ||ue||          over B
// acc[2] = sum ||ie||          over B*K
//
// LDS-free version: one b per wave.
//  - 13 quarter-wave dwordx4 loads per b keep the fully-coalesced gather
//    (16 lanes x 16B = one contiguous 256B row per quarter).
//  - lane l16 holds ue chunk [l16*4 .. l16*4+3] in registers (float4), so the
//    row-dot is 4 FMAs + a 16-lane DPP tree reduction (quad_perm x2 +
//    row_ror:4/8) -- pure VALU, no LDS pipe, no barriers, no 52KB staging
//    buffer. LDS drops to 48B -> occupancy becomes VGPR-bound (~2x waves/CU),
//    which is what a random-gather kernel needs to saturate HBM.
//  - (dot, sq) for row k end in lane (k&3)*16 + (k>>2); one ds_bpermute pair
//    routes them to lane k for the coalesced 200B store.
template<int CTRL>
__device__ __forceinline__ float dpp_movf(float x) {
    return __int_as_float(__builtin_amdgcn_update_dpp(
        0, __float_as_int(x), CTRL, 0xF, 0xF, true));
}

// Sum across each 16-lane row; all 16 lanes end with the total. Pure VALU.
__device__ __forceinline__ float row16_sum(float x) {
    x += dpp_movf<0xB1>(x);    // quad_perm [1,0,3,2]  (xor 1)
    x += dpp_movf<0x4E>(x);    // quad_perm [2,3,0,1]  (xor 2)
    x += dpp_movf<0x124>(x);   // row_ror:4  -> quad i + quad i+1
    x += dpp_movf<0x128>(x);   // row_ror:8  -> all four quads
    return x;
}

__global__ __launch_bounds__(256, 5) void mf_main(
    const float* __restrict__ user_weight,   // [NU, H]
    const float* __restrict__ item_weight,   // [NI, H]
    const float* __restrict__ user_bias,     // [NU, 1]
    const float* __restrict__ item_bias,     // [NI, 1]
    const float* __restrict__ gbias,         // [1]
    const float* __restrict__ target,        // [B, K]
    const int*   __restrict__ user,          // [B]
    const int*   __restrict__ item,          // [B, K]
    float* __restrict__ out,                 // [B*K + 1]
    float* __restrict__ acc)                 // [3] zeroed
{
    const int tid  = threadIdx.x;
    const int wave = tid >> 6;
    const int lane = tid & 63;
    const int q    = lane >> 4;   // quarter id: which row of the group of 4
    const int l16  = lane & 15;   // float4 chunk within a 256B row
    const bool active = (lane < NK);
    const int kcl  = active ? lane : (NK - 1);

    __shared__ float s_red[3][4];

    const int b = blockIdx.x * 4 + wave;     // one b per wave

    const float gb = gbias[0];

    const int   u    = user[b];
    const float ubv  = user_bias[u];
    const int   kidx = item[b * NK + kcl];   // lane k's own row index
    const float tgt  = target[b * NK + kcl];
    const float ibv  = item_bias[kidx];      // lane k's own row bias

    // ue chunk for this lane (replicated across the 4 quarters; L1 absorbs)
    float4 uv = *reinterpret_cast<const float4*>(
        user_weight + (size_t)u * NH + (l16 << 2));
    uv.x += ubv; uv.y += ubv; uv.z += ubv; uv.w += ubv;

    // ---- issue all 13 coalesced row gathers (max per-wave MLP) ----
    float4 r[NGRP];
    #pragma unroll
    for (int gr = 0; gr < NGRP; ++gr) {
        const int k  = gr * 4 + q;
        const int kk = (k < NK) ? k : (NK - 1);
        const int it = __shfl(kidx, kk);     // broadcast row index to quarter
        r[gr] = *reinterpret_cast<const float4*>(
            item_weight + (size_t)it * NH + (l16 << 2));
    }

    // ---- consume: quarter q dots row gr*4+q in-register, DPP reduce ----
    float keep_dot = 0.f, keep_sq = 0.f;
    #pragma unroll
    for (int gr = 0; gr < NGRP; ++gr) {
        const int k  = gr * 4 + q;
        const int kk = (k < NK) ? k : (NK - 1);
        const float ibk = __shfl(ibv, kk);   // row bias, quarter-uniform
        const float iex = r[gr].x + ibk;
        const float iey = r[gr].y + ibk;
        const float iez = r[gr].z + ibk;
        const float iew = r[gr].w + ibk;
        float pd = iex * uv.x + iey * uv.y + iez * uv.z + iew * uv.w;
        float ps = iex * iex  + iey * iey  + iez * iez  + iew * iew;
        pd = row16_sum(pd);
        ps = row16_sum(ps);
        if (l16 == gr) { keep_dot = pd; keep_sq = ps; }   // cndmask keep
    }

    // ---- route (dot, sq) of row k to lane k: k lives in lane (k&3)*16+(k>>2)
    const int srcl = ((kcl & 3) << 4) + (kcl >> 2);
    const float dot = __shfl(keep_dot, srcl);
    const float sq  = __shfl(keep_sq,  srcl);

    // ---- user norm (all lanes hold the same row16 total) ----
    float us = uv.x * uv.x + uv.y * uv.y + uv.z * uv.z + uv.w * uv.w;
    us = row16_sum(us);

    float mse_acc = 0.f, ien_acc = 0.f;
    const float pred = dot + gb;
    if (active) {
        out[b * NK + lane] = pred;           // coalesced 200B store
        const float d = pred - tgt;
        mse_acc = d * d;
        ien_acc = sqrtf(sq);
    }

    // ---- wave reduction ----
    #pragma unroll
    for (int off = 32; off > 0; off >>= 1) {
        mse_acc += __shfl_down(mse_acc, off);
        ien_acc += __shfl_down(ien_acc, off);
    }
    if (lane == 0) {
        s_red[0][wave] = mse_acc;
        s_red[1][wave] = sqrtf(us);          // one ||ue|| per wave (per b)
        s_red[2][wave] = ien_acc;
    }
    __syncthreads();
    if (tid == 0) {
        atomicAdd(&acc[0], s_red[0][0] + s_red[0][1] + s_red[0][2] + s_red[0][3]);
        atomicAdd(&acc[1], s_red[1][0] + s_red[1][1] + s_red[1][2] + s_red[1][3]);
        atomicAdd(&acc[2], s_red[2][0] + s_red[2][1] + s_red[2][2] + s_red[2][3]);
    }
}

__global__ void mf_finish(const float* __restrict__ acc, float* __restrict__ out)
{
    const float inv_bk = 1.0f / (float)(NB * NK);
    const float mse = acc[0] * inv_bk;
    const float loss = mse + REG * (acc[1] / (float)NB) + REG * (acc[2] * inv_bk);
    out[NB * NK] = loss;
}

extern "C" void kernel_launch(void* const* d_in, const int* in_sizes, int n_in,
                              void* d_out, int out_size, void* d_ws, size_t ws_size,
                              hipStream_t stream) {
    const float* user_weight = (const float*)d_in[0];
    const float* item_weight = (const float*)d_in[1];
    const float* user_bias   = (const float*)d_in[2];
    const float* item_bias   = (const float*)d_in[3];
    const float* gbias       = (const float*)d_in[4];
    const float* target      = (const float*)d_in[5];
    const int*   user        = (const int*)d_in[6];
    const int*   item        = (const int*)d_in[7];
    float* out = (float*)d_out;
    float* acc = (float*)d_ws;

    hipMemsetAsync(acc, 0, 3 * sizeof(float), stream);
    mf_main<<<NB / 4, 256, 0, stream>>>(user_weight, item_weight, user_bias, item_bias,
                                        gbias, target, user, item, out, acc);
    mf_finish<<<1, 1, 0, stream>>>(acc, out);
}

// Round 2
// 368.131 us; speedup vs baseline: 1.2586x; 1.2586x over previous
//
#include <hip/hip_runtime.h>

// Problem constants (match reference)
constexpr int NB = 16384;   // B
constexpr int NK = 50;      // K
constexpr int NH = 64;      // H
constexpr float REG = 0.01f;
constexpr int NGRP = 13;    // ceil(NK/4) row-groups (quarter-wave = one row)
constexpr int G = 4;        // b's per wave, software-pipelined

// acc[0] = sum (pred-target)^2 over B*K
// acc[1] = sum ||ue||          over B
// acc[2] = sum ||ie||          over B*K
//
// Register-pipelined, LDS-free:
//  - 13 quarter-wave dwordx4 loads per b (fully-coalesced 256B row gathers).
//  - rA/rB float4[13] ping-pong: next b's gathers are in flight while the
//    current b is consumed -> steady-state ~13 row loads outstanding per wave
//    (round 1's one-shot version had a ~50% duty cycle -> 867 GB/s only).
//  - index loads issued 2 b's ahead, dependent gathers (user_bias/item_bias/
//    user row) 1 b ahead: the kidx->shfl->gather chain never blocks consume.
//  - item bias folded analytically: pred = dot(ie,ue) + ib*sum(ue);
//    ||ie+ib||^2 = sum(ie^2) + 2*ib*sum(ie) + 64*ib^2. Lane k already holds
//    row k's ib, so no per-group __shfl of biases in the hot loop.
//  - consume is pure VALU: 4 FMAs x3 + 16-lane DPP tree reductions.

template<int CTRL>
__device__ __forceinline__ float dpp_movf(float x) {
    return __int_as_float(__builtin_amdgcn_update_dpp(
        0, __float_as_int(x), CTRL, 0xF, 0xF, true));
}

// Sum across each 16-lane row; all 16 lanes end with the total. Pure VALU.
__device__ __forceinline__ float row16_sum(float x) {
    x += dpp_movf<0xB1>(x);    // quad_perm [1,0,3,2]  (xor 1)
    x += dpp_movf<0x4E>(x);    // quad_perm [2,3,0,1]  (xor 2)
    x += dpp_movf<0x124>(x);   // row_ror:4
    x += dpp_movf<0x128>(x);   // row_ror:8
    return x;
}

__global__ __launch_bounds__(256, 3) void mf_main(
    const float* __restrict__ user_weight,   // [NU, H]
    const float* __restrict__ item_weight,   // [NI, H]
    const float* __restrict__ user_bias,     // [NU, 1]
    const float* __restrict__ item_bias,     // [NI, 1]
    const float* __restrict__ gbias,         // [1]
    const float* __restrict__ target,        // [B, K]
    const int*   __restrict__ user,          // [B]
    const int*   __restrict__ item,          // [B, K]
    float* __restrict__ out,                 // [B*K + 1]
    float* __restrict__ acc)                 // [3] zeroed
{
    const int tid  = threadIdx.x;
    const int wave = tid >> 6;
    const int lane = tid & 63;
    const int q    = lane >> 4;   // quarter id: which row of the group of 4
    const int l16  = lane & 15;   // float4 chunk within a 256B row
    const bool active = (lane < NK);
    const int kcl  = active ? lane : (NK - 1);
    const int srcl = ((kcl & 3) << 4) + (kcl >> 2);  // lane holding row k's sums

    __shared__ float s_red[3][4];

    const int b0 = (blockIdx.x * 4 + wave) * G;
    const float gb = gbias[0];

    // 3 rotating operand slots (A,B,C) + 2 row buffers (rA,rB)
    int   uA, uB, uC;
    int   kxA, kxB, kxC;
    float tgA, tgB, tgC;
    float ubA, ubB, ubC;
    float ibA, ibB, ibC;
    float4 uvA, uvB, uvC;
    float4 rA[NGRP], rB[NGRP];

    float mse_acc = 0.f, ien_acc = 0.f, uen_acc = 0.f;

#define IDXA(S, bb) do { \
    uA##S  = user[(bb)]; \
    kxA##S = item[(bb) * NK + kcl]; \
    tgA##S = target[(bb) * NK + kcl]; \
} while (0)
// (token-paste trick: IDXA(A,b) -> uAA... avoid; use explicit macros instead)
#undef IDXA

#define IDX_A(U, KX, TG, bb) do { \
    U  = user[(bb)]; \
    KX = item[(bb) * NK + kcl]; \
    TG = target[(bb) * NK + kcl]; \
} while (0)

#define IDX_B(UB, IB, UV, U, KX) do { \
    UB = user_bias[U]; \
    IB = item_bias[KX]; \
    UV = *reinterpret_cast<const float4*>(user_weight + (size_t)(U) * NH + (l16 << 2)); \
} while (0)

#define GATH(RR, KX) do { \
    _Pragma("unroll") \
    for (int gr = 0; gr < NGRP; ++gr) { \
        const int k  = gr * 4 + q; \
        const int kk = (k < NK) ? k : (NK - 1); \
        const int it = __shfl(KX, kk); \
        RR[gr] = *reinterpret_cast<const float4*>(item_weight + (size_t)it * NH + (l16 << 2)); \
    } \
} while (0)

#define CONSUME(bb, RR, UB, IB, UV, TG) do { \
    float4 ue = UV; \
    ue.x += UB; ue.y += UB; ue.z += UB; ue.w += UB; \
    float us = ue.x * ue.x + ue.y * ue.y + ue.z * ue.z + ue.w * ue.w; \
    float su = ue.x + ue.y + ue.z + ue.w; \
    us = row16_sum(us); \
    su = row16_sum(su); \
    if (lane == 0) uen_acc += sqrtf(us); \
    float kd = 0.f, ks = 0.f, kp = 0.f; \
    _Pragma("unroll") \
    for (int gr = 0; gr < NGRP; ++gr) { \
        float pd = RR[gr].x * ue.x + RR[gr].y * ue.y + RR[gr].z * ue.z + RR[gr].w * ue.w; \
        float ps = RR[gr].x * RR[gr].x + RR[gr].y * RR[gr].y + RR[gr].z * RR[gr].z + RR[gr].w * RR[gr].w; \
        float pp = RR[gr].x + RR[gr].y + RR[gr].z + RR[gr].w; \
        pd = row16_sum(pd); \
        ps = row16_sum(ps); \
        pp = row16_sum(pp); \
        if (l16 == gr) { kd = pd; ks = ps; kp = pp; } \
    } \
    const float dot = __shfl(kd, srcl); \
    const float sq0 = __shfl(ks, srcl); \
    const float sm  = __shfl(kp, srcl); \
    if (active) { \
        const float pred = dot + (IB) * su + gb; \
        out[(bb) * NK + lane] = pred; \
        const float d = pred - (TG); \
        mse_acc += d * d; \
        const float sq = sq0 + 2.f * (IB) * sm + 64.f * (IB) * (IB); \
        ien_acc += sqrtf(sq); \
    } \
} while (0)

    // ---- prologue ----
    IDX_A(uA, kxA, tgA, b0 + 0);
    IDX_B(ubA, ibA, uvA, uA, kxA);       // one unavoidable index-latency stall
    GATH(rA, kxA);
    IDX_A(uB, kxB, tgB, b0 + 1);

    // ---- pipelined main: gather(next) in flight during consume(cur) ----
    // g=0
    IDX_B(ubB, ibB, uvB, uB, kxB);
    GATH(rB, kxB);
    CONSUME(b0 + 0, rA, ubA, ibA, uvA, tgA);
    IDX_A(uC, kxC, tgC, b0 + 2);
    // g=1
    IDX_B(ubC, ibC, uvC, uC, kxC);
    GATH(rA, kxC);
    CONSUME(b0 + 1, rB, ubB, ibB, uvB, tgB);
    IDX_A(uA, kxA, tgA, b0 + 3);
    // g=2
    IDX_B(ubA, ibA, uvA, uA, kxA);
    GATH(rB, kxA);
    CONSUME(b0 + 2, rA, ubC, ibC, uvC, tgC);
    // g=3
    CONSUME(b0 + 3, rB, ubA, ibA, uvA, tgA);

#undef IDX_A
#undef IDX_B
#undef GATH
#undef CONSUME

    // ---- one wave reduction at the end ----
    #pragma unroll
    for (int off = 32; off > 0; off >>= 1) {
        mse_acc += __shfl_down(mse_acc, off);
        ien_acc += __shfl_down(ien_acc, off);
    }
    if (lane == 0) {
        s_red[0][wave] = mse_acc;
        s_red[1][wave] = uen_acc;
        s_red[2][wave] = ien_acc;
    }
    __syncthreads();
    if (tid == 0) {
        atomicAdd(&acc[0], s_red[0][0] + s_red[0][1] + s_red[0][2] + s_red[0][3]);
        atomicAdd(&acc[1], s_red[1][0] + s_red[1][1] + s_red[1][2] + s_red[1][3]);
        atomicAdd(&acc[2], s_red[2][0] + s_red[2][1] + s_red[2][2] + s_red[2][3]);
    }
}

__global__ void mf_finish(const float* __restrict__ acc, float* __restrict__ out)
{
    const float inv_bk = 1.0f / (float)(NB * NK);
    const float mse = acc[0] * inv_bk;
    const float loss = mse + REG * (acc[1] / (float)NB) + REG * (acc[2] * inv_bk);
    out[NB * NK] = loss;
}

extern "C" void kernel_launch(void* const* d_in, const int* in_sizes, int n_in,
                              void* d_out, int out_size, void* d_ws, size_t ws_size,
                              hipStream_t stream) {
    const float* user_weight = (const float*)d_in[0];
    const float* item_weight = (const float*)d_in[1];
    const float* user_bias   = (const float*)d_in[2];
    const float* item_bias   = (const float*)d_in[3];
    const float* gbias       = (const float*)d_in[4];
    const float* target      = (const float*)d_in[5];
    const int*   user        = (const int*)d_in[6];
    const int*   item        = (const int*)d_in[7];
    float* out = (float*)d_out;
    float* acc = (float*)d_ws;

    hipMemsetAsync(acc, 0, 3 * sizeof(float), stream);
    mf_main<<<NB / (4 * G), 256, 0, stream>>>(user_weight, item_weight, user_bias, item_bias,
                                              gbias, target, user, item, out, acc);
    mf_finish<<<1, 1, 0, stream>>>(acc, out);
}